// Round 7
// baseline (94.004 us; speedup 1.0000x reference)
//
#include <hip/hip_runtime.h>

#define N_  8
#define D_  64
#define H_  64
#define W_  64
#define HW_ (H_ * W_)
#define KK  25

// ---------------------------------------------------------------------------
// Kernel 1: per-block nonzero partial counts of cur and prev; also streams
// prev_mem (partials to pr, never consumed) to warm L3 for kernel 2.
// 512 blocks x 256 threads, 4096 elems/block, 64 blocks per batch.
// ---------------------------------------------------------------------------
__global__ __launch_bounds__(256) void count_nz_kernel(
    const float4* __restrict__ cur, const float4* __restrict__ prev,
    const float4* __restrict__ pmv,
    unsigned int* __restrict__ pc, unsigned int* __restrict__ pq,
    unsigned int* __restrict__ pr)
{
    __shared__ unsigned int sc[4], sp[4], sr[4];
    const int t    = threadIdx.x;
    const int wid  = t >> 6;
    const int lane = t & 63;

    unsigned int wc = 0, wp = 0, wr = 0;
#pragma unroll
    for (int j = 0; j < 4; ++j) {
        int idx = blockIdx.x * 1024 + j * 256 + t;
        float4 a = cur[idx];
        float4 b = prev[idx];
        float4 m = pmv[idx];
        wc += (unsigned)__popcll(__ballot(a.x != 0.f));
        wc += (unsigned)__popcll(__ballot(a.y != 0.f));
        wc += (unsigned)__popcll(__ballot(a.z != 0.f));
        wc += (unsigned)__popcll(__ballot(a.w != 0.f));
        wp += (unsigned)__popcll(__ballot(b.x != 0.f));
        wp += (unsigned)__popcll(__ballot(b.y != 0.f));
        wp += (unsigned)__popcll(__ballot(b.z != 0.f));
        wp += (unsigned)__popcll(__ballot(b.w != 0.f));
        wr += (unsigned)__popcll(__ballot(m.x != 0.f));
        wr += (unsigned)__popcll(__ballot(m.y != 0.f));
        wr += (unsigned)__popcll(__ballot(m.z != 0.f));
        wr += (unsigned)__popcll(__ballot(m.w != 0.f));
    }
    if (lane == 0) { sc[wid] = wc; sp[wid] = wp; sr[wid] = wr; }
    __syncthreads();
    if (t == 0) {
        pc[blockIdx.x] = sc[0] + sc[1] + sc[2] + sc[3];
        pq[blockIdx.x] = sp[0] + sp[1] + sp[2] + sp[3];
        pr[blockIdx.x] = sr[0] + sr[1] + sr[2] + sr[3];
    }
}

// ---------------------------------------------------------------------------
// Kernel 2: fused FeatureAlign, float2-vectorized, 2 blocks/CU (16 waves/CU).
// Grid: 512 blocks = (n, y). Block: 512 threads = 8 waves; wave dg (uniform)
// covers channels dg*8..dg*8+7; lane = (s, xq): half-wave s takes 4 channels,
// xq = float2 pixel pair of row y. s folds into the per-lane byte offset so
// all loads stay saddr-form. Half-wave partials combined via shfl_xor(32);
// LDS red[4][25][64] = 25.6 KB -> 2 blocks/CU resident.
// ---------------------------------------------------------------------------
__global__ __launch_bounds__(512, 4) void feature_align_kernel(
    const float* __restrict__ cur, const float* __restrict__ prev,
    const float* __restrict__ pm, float* __restrict__ out,
    const unsigned int* __restrict__ pc, const unsigned int* __restrict__ pq)
{
    __shared__ float red[4][KK][64];    // 25.6 KB; aliased: red[0]=wght, red[1][0]=zflag

    const int b    = blockIdx.x;                 // 0..511
    const int n    = b >> 6;                     // batch
    const int y    = b & 63;                     // row
    const int lane = threadIdx.x & 63;
    const int dg   = __builtin_amdgcn_readfirstlane(threadIdx.x >> 6); // 0..7
    const int s    = lane >> 5;                  // half-wave: channel sub-group
    const int xq   = lane & 31;
    const int x0   = xq * 2;

    // d-invariant per-lane byte offsets; s*4 channels folded in (s*65536 B).
    const unsigned laneoff = (unsigned)s * 4u * HW_ * 4u;
    int cb[3];
#pragma unroll
    for (int i = 0; i < 3; ++i)
        cb[i] = min(max(x0 - 2 + 2 * i, 0), W_ - 2);     // even -> 8B aligned
    unsigned voff[5][3];
#pragma unroll
    for (int ky = 0; ky < 5; ++ky) {
        int qy = min(max(y + ky - 2, 0), H_ - 1);
#pragma unroll
        for (int i = 0; i < 3; ++i)
            voff[ky][i] = laneoff + (unsigned)((qy * W_ + cb[i]) * 4);
    }
    const unsigned curoff = laneoff + (unsigned)((y * W_ + x0) * 4);

    const size_t nbase = (size_t)n * D_ * HW_;
    const char* curb  = (const char*)(cur  + nbase + (size_t)dg * 8 * HW_);
    const char* prevb = (const char*)(prev + nbase + (size_t)dg * 8 * HW_);
    const char* pmb   = (const char*)(pm   + nbase + (size_t)dg * 8 * HW_);
    char*       outb  = (char*)(out + nbase + (size_t)dg * 8 * HW_);

    // ---- EARLY prefetch: pm centers (4 channels) + count partials ----
    float2 pmc[4];
#pragma unroll
    for (int dd = 0; dd < 4; ++dd)
        pmc[dd] = *(const float2*)(pmb + (size_t)dd * HW_ * 4 + curoff);
    unsigned int ccnt = 0, vcnt = 0;
    if (dg == 0) {                       // wave-uniform branch
        ccnt = pc[(n << 6) + lane];
        vcnt = pq[(n << 6) + lane];
    }

    float acc0[KK], acc1[KK];
#pragma unroll
    for (int k = 0; k < KK; ++k) { acc0[k] = 0.f; acc1[k] = 0.f; }

    // ---- dot phase: 4 channels/thread, contiguous float2 saddr loads ----
#pragma unroll
    for (int dd = 0; dd < 4; ++dd) {
        const char* cch = curb  + (size_t)dd * HW_ * 4;
        const char* pch = prevb + (size_t)dd * HW_ * 4;
        float2 c = *(const float2*)(cch + curoff);
        float2 t[5][3];
#pragma unroll
        for (int ky = 0; ky < 5; ++ky)
#pragma unroll
            for (int i = 0; i < 3; ++i)
                t[ky][i] = *(const float2*)(pch + voff[ky][i]);
#pragma unroll
        for (int ky = 0; ky < 5; ++ky) {
            float v[6] = { t[ky][0].x, t[ky][0].y, t[ky][1].x,
                           t[ky][1].y, t[ky][2].x, t[ky][2].y };
#pragma unroll
            for (int kx = 0; kx < 5; ++kx) {
                acc0[ky * 5 + kx] = fmaf(c.x, v[kx],     acc0[ky * 5 + kx]);
                acc1[ky * 5 + kx] = fmaf(c.y, v[kx + 1], acc1[ky * 5 + kx]);
            }
        }
    }

    // ---- combine half-waves (s=0 + s=1 cover same pixels, diff channels) ----
#pragma unroll
    for (int k = 0; k < KK; ++k) {
        acc0[k] += __shfl_xor(acc0[k], 32);
        acc1[k] += __shfl_xor(acc1[k], 32);
    }

    // ---- cross-dg reduction: dg 0-3 write, dg 4-7 add in place ----
    if (dg < 4) {
        if (s == 0)
#pragma unroll
            for (int k = 0; k < KK; ++k)
                *(float2*)&red[dg][k][x0] = make_float2(acc0[k], acc1[k]);
    }
    __syncthreads();
    if (dg >= 4) {
        if (s == 0)
#pragma unroll
            for (int k = 0; k < KK; ++k) {
                float2 t2 = *(float2*)&red[dg - 4][k][x0];
                t2.x += acc0[k]; t2.y += acc1[k];
                *(float2*)&red[dg - 4][k][x0] = t2;
            }
    }
    __syncthreads();

    // ---- weights: wave 0, one pixel per lane ----
    if (dg == 0) {
        const int pix = lane;            // 0..63, x coordinate in row y
        unsigned int cc = ccnt, vv = vcnt;
#pragma unroll
        for (int st = 32; st >= 1; st >>= 1) {
            cc += __shfl_xor(cc, st);
            vv += __shfl_xor(vv, st);
        }
        float scale = 1.0f / (((float)cc + 1e-8f) * ((float)vv + 1e-8f));

        float mass = 0.f;
        float cf[KK];
#pragma unroll
        for (int k = 0; k < KK; ++k) {
            float sm = red[0][k][pix] + red[1][k][pix]
                     + red[2][k][pix] + red[3][k][pix];
            int ky = k / 5, kx = k % 5;
            int py  = y + ky - 2;
            int pxc = pix + kx - 2;
            bool val = (py >= 0) && (py < H_) && (pxc >= 0) && (pxc < W_);
            float c = val ? fmaxf(sm * scale, 0.f) : 0.f;
            cf[k] = c;
            mass += c;
        }
        bool  zero = fabsf(mass) < 1e-7f;
        float inv  = zero ? 0.f : 1.0f / mass;
        // Per-column alias-safe (this lane read red[*][*][pix] above).
#pragma unroll
        for (int k = 0; k < KK; ++k) red[0][k][pix] = cf[k] * inv;  // wght
        red[1][0][pix] = zero ? 1.f : 0.f;                          // zflag
    }
    __syncthreads();

    // ---- output phase ----
    const float zf0 = red[1][0][x0];
    const float zf1 = red[1][0][x0 + 1];

    if (zf0 != 0.f && zf1 != 0.f) {
        // Hot path: pure stores of prefetched pm centers.
#pragma unroll
        for (int dd = 0; dd < 4; ++dd)
            *(float2*)(outb + (size_t)dd * HW_ * 4 + curoff) = pmc[dd];
    } else {
        float w0[KK], w1[KK];
#pragma unroll
        for (int k = 0; k < KK; ++k) {
            float2 ww = *(float2*)&red[0][k][x0];
            w0[k] = ww.x; w1[k] = ww.y;
        }
#pragma unroll
        for (int dd = 0; dd < 4; ++dd) {
            const char* pch = pmb + (size_t)dd * HW_ * 4;
            float2 t2[5][3];
#pragma unroll
            for (int ky = 0; ky < 5; ++ky)
#pragma unroll
                for (int i = 0; i < 3; ++i)
                    t2[ky][i] = *(const float2*)(pch + voff[ky][i]);
            float v0 = 0.f, v1 = 0.f;
#pragma unroll
            for (int ky = 0; ky < 5; ++ky) {
                float v[6] = { t2[ky][0].x, t2[ky][0].y, t2[ky][1].x,
                               t2[ky][1].y, t2[ky][2].x, t2[ky][2].y };
#pragma unroll
                for (int kx = 0; kx < 5; ++kx) {
                    v0 = fmaf(w0[ky * 5 + kx], v[kx],     v0);
                    v1 = fmaf(w1[ky * 5 + kx], v[kx + 1], v1);
                }
            }
            float2 o;
            o.x = (zf0 != 0.f) ? pmc[dd].x : v0;
            o.y = (zf1 != 0.f) ? pmc[dd].y : v1;
            *(float2*)(outb + (size_t)dd * HW_ * 4 + curoff) = o;
        }
    }
}

extern "C" void kernel_launch(void* const* d_in, const int* in_sizes, int n_in,
                              void* d_out, int out_size, void* d_ws, size_t ws_size,
                              hipStream_t stream)
{
    const float* cur  = (const float*)d_in[0];
    const float* prev = (const float*)d_in[1];
    const float* pm   = (const float*)d_in[2];
    float*       out  = (float*)d_out;
    unsigned int* pc  = (unsigned int*)d_ws;        // 512 partials (cur)
    unsigned int* pq  = pc + 512;                   // 512 partials (prev)
    unsigned int* pr  = pq + 512;                   // 512 partials (pm, unused)

    count_nz_kernel<<<512, 256, 0, stream>>>(
        (const float4*)cur, (const float4*)prev, (const float4*)pm, pc, pq, pr);

    feature_align_kernel<<<512, 512, 0, stream>>>(cur, prev, pm, out, pc, pq);
}

// Round 8
// 90.706 us; speedup vs baseline: 1.0364x; 1.0364x over previous
//
#include <hip/hip_runtime.h>

#define N_  8
#define D_  64
#define H_  64
#define W_  64
#define HW_ (H_ * W_)
#define KK  25

// ---------------------------------------------------------------------------
// Kernel 1: per-block nonzero partial counts of cur and prev; also streams
// prev_mem (partials to pr, never consumed) to warm L3 for kernel 2.
// 512 blocks x 256 threads, 4096 elems/block, 64 blocks per batch.
// ---------------------------------------------------------------------------
__global__ __launch_bounds__(256) void count_nz_kernel(
    const float4* __restrict__ cur, const float4* __restrict__ prev,
    const float4* __restrict__ pmv,
    unsigned int* __restrict__ pc, unsigned int* __restrict__ pq,
    unsigned int* __restrict__ pr)
{
    __shared__ unsigned int sc[4], sp[4], sr[4];
    const int t    = threadIdx.x;
    const int wid  = t >> 6;
    const int lane = t & 63;

    unsigned int wc = 0, wp = 0, wr = 0;
#pragma unroll
    for (int j = 0; j < 4; ++j) {
        int idx = blockIdx.x * 1024 + j * 256 + t;
        float4 a = cur[idx];
        float4 b = prev[idx];
        float4 m = pmv[idx];
        wc += (unsigned)__popcll(__ballot(a.x != 0.f));
        wc += (unsigned)__popcll(__ballot(a.y != 0.f));
        wc += (unsigned)__popcll(__ballot(a.z != 0.f));
        wc += (unsigned)__popcll(__ballot(a.w != 0.f));
        wp += (unsigned)__popcll(__ballot(b.x != 0.f));
        wp += (unsigned)__popcll(__ballot(b.y != 0.f));
        wp += (unsigned)__popcll(__ballot(b.z != 0.f));
        wp += (unsigned)__popcll(__ballot(b.w != 0.f));
        wr += (unsigned)__popcll(__ballot(m.x != 0.f));
        wr += (unsigned)__popcll(__ballot(m.y != 0.f));
        wr += (unsigned)__popcll(__ballot(m.z != 0.f));
        wr += (unsigned)__popcll(__ballot(m.w != 0.f));
    }
    if (lane == 0) { sc[wid] = wc; sp[wid] = wp; sr[wid] = wr; }
    __syncthreads();
    if (t == 0) {
        pc[blockIdx.x] = sc[0] + sc[1] + sc[2] + sc[3];
        pq[blockIdx.x] = sp[0] + sp[1] + sp[2] + sp[3];
        pr[blockIdx.x] = sr[0] + sr[1] + sr[2] + sr[3];
    }
}

// ---------------------------------------------------------------------------
// Kernel 2: fused FeatureAlign, LDS-staged.
// Grid: 512 blocks = (n, y). Block: 256 threads = 32 px-pairs x 8 ch-groups.
// Per 16-channel chunk: stage prev rows y-2..y+2 (clamped) via 5 independent
// dwordx4/thread (high MLP, coalesced), then window dots from LDS
// (ds_read_b64, 2-way conflicts = free). x-halo = LDS pad garbage, y-halo =
// row clamp; both feed only invalid-masked k. cur/pm centers + counts
// prefetched at top. LDS union: stage 16x5x72 (23KB) / red[4][25][64]
// (25.6KB) -> 2 blocks/CU.
// ---------------------------------------------------------------------------
__global__ __launch_bounds__(256, 2) void feature_align_kernel(
    const float* __restrict__ cur, const float* __restrict__ prev,
    const float* __restrict__ pm, float* __restrict__ out,
    const unsigned int* __restrict__ pc, const unsigned int* __restrict__ pq)
{
    __shared__ __align__(16) float ls[6400];   // 25.6 KB union

    const int b   = blockIdx.x;                // 0..511
    const int n   = b >> 6;                    // batch
    const int y   = b & 63;                    // row
    const int tid = threadIdx.x;
    const int xp  = tid & 31;                  // px-pair
    const int g   = tid >> 5;                  // ch-group 0..7 (wave-half uniform)
    const int x0  = xp * 2;

    // Clamped window rows (block-uniform -> SGPRs).
    int qy[5];
#pragma unroll
    for (int ky = 0; ky < 5; ++ky)
        qy[ky] = min(max(y + ky - 2, 0), H_ - 1);

    const size_t chbase = (size_t)n * D_;      // channel index base

    // ---- EARLY prefetch: cur + pm centers for this thread's 8 channels ----
    // channel j -> ch = (j>>1)*16 + g*2 + (j&1)   (chunk (j>>1), sub (j&1))
    float2 cv[8], pmc[8];
#pragma unroll
    for (int j = 0; j < 8; ++j) {
        int ch = ((j >> 1) << 4) + g * 2 + (j & 1);
        const float* cp = cur + (chbase + ch) * HW_ + y * W_ + x0;
        const float* mp = pm  + (chbase + ch) * HW_ + y * W_ + x0;
        cv[j]  = *(const float2*)cp;
        pmc[j] = *(const float2*)mp;
    }
    // Count partials (wave 0 only; used in weights phase).
    unsigned int ccnt = 0, vcnt = 0;
    if (tid < 64) {
        ccnt = pc[(n << 6) + tid];
        vcnt = pq[(n << 6) + tid];
    }

    float acc0[KK], acc1[KK];
#pragma unroll
    for (int k = 0; k < KK; ++k) { acc0[k] = 0.f; acc1[k] = 0.f; }

    // Staging thread mapping: c = tid>>4 (16 ch), xf = tid&15 (16 float4/row).
    const int sc_ = tid >> 4;
    const int sxf = tid & 15;

    // ---- chunk loop: 4 x 16 channels ----
#pragma unroll
    for (int cc = 0; cc < 4; ++cc) {
        // stage: 5 independent dwordx4 per thread (rows qy[0..4])
#pragma unroll
        for (int r = 0; r < 5; ++r) {
            const float4 v4 = *(const float4*)(
                prev + (chbase + cc * 16 + sc_) * HW_ + qy[r] * W_ + 4 * sxf);
            *(float4*)&ls[sc_ * 360 + r * 72 + 4 + 4 * sxf] = v4;
        }
        __syncthreads();

        // compute: 2 channels for this group, window dots from LDS
#pragma unroll
        for (int j2 = 0; j2 < 2; ++j2) {
            const int cloc = g * 2 + j2;
            const float2 c2 = cv[cc * 2 + j2];
#pragma unroll
            for (int r = 0; r < 5; ++r) {
                const float* row = &ls[cloc * 360 + r * 72];
                float2 a = *(const float2*)&row[x0 + 2];   // data cols x0-2,x0-1
                float2 bq = *(const float2*)&row[x0 + 4];  // x0, x0+1
                float2 d = *(const float2*)&row[x0 + 6];   // x0+2, x0+3
                float v[6] = { a.x, a.y, bq.x, bq.y, d.x, d.y };
#pragma unroll
                for (int kx = 0; kx < 5; ++kx) {
                    acc0[r * 5 + kx] = fmaf(c2.x, v[kx],     acc0[r * 5 + kx]);
                    acc1[r * 5 + kx] = fmaf(c2.y, v[kx + 1], acc1[r * 5 + kx]);
                }
            }
        }
        __syncthreads();   // protect LDS before next stage / red write
    }

    // ---- cross-group reduction into red[4][25][64] (aliases stage) ----
    if (g < 4) {           // waves 0,1
#pragma unroll
        for (int k = 0; k < KK; ++k)
            *(float2*)&ls[g * 1600 + k * 64 + x0] = make_float2(acc0[k], acc1[k]);
    }
    __syncthreads();
    if (g >= 4) {          // waves 2,3 add in place
#pragma unroll
        for (int k = 0; k < KK; ++k) {
            float2 t2 = *(float2*)&ls[(g - 4) * 1600 + k * 64 + x0];
            t2.x += acc0[k]; t2.y += acc1[k];
            *(float2*)&ls[(g - 4) * 1600 + k * 64 + x0] = t2;
        }
    }
    __syncthreads();

    // ---- weights: wave 0, one pixel per lane ----
    if (tid < 64) {
        const int px = tid;
        unsigned int cc2 = ccnt, vv = vcnt;
#pragma unroll
        for (int st = 32; st >= 1; st >>= 1) {
            cc2 += __shfl_xor(cc2, st);
            vv  += __shfl_xor(vv, st);
        }
        float scale = 1.0f / (((float)cc2 + 1e-8f) * ((float)vv + 1e-8f));

        float mass = 0.f;
        float cf[KK];
#pragma unroll
        for (int k = 0; k < KK; ++k) {
            float sm = ls[k * 64 + px]        + ls[1600 + k * 64 + px]
                     + ls[3200 + k * 64 + px] + ls[4800 + k * 64 + px];
            int ky = k / 5, kx = k % 5;
            int py  = y + ky - 2;
            int pxc = px + kx - 2;
            bool val = (py >= 0) && (py < H_) && (pxc >= 0) && (pxc < W_);
            float c = val ? fmaxf(sm * scale, 0.f) : 0.f;
            cf[k] = c;
            mass += c;
        }
        bool  zero = fabsf(mass) < 1e-7f;
        float inv  = zero ? 0.f : 1.0f / mass;
        // Column px is only touched by this lane -> alias-safe rewrites.
#pragma unroll
        for (int k = 0; k < KK; ++k) ls[k * 64 + px] = cf[k] * inv;  // wght
        ls[1600 + px] = zero ? 1.f : 0.f;                            // zflag
    }
    __syncthreads();

    // ---- output phase ----
    const float zf0 = ls[1600 + x0];
    const float zf1 = ls[1600 + x0 + 1];

    if (zf0 != 0.f && zf1 != 0.f) {
        // Hot path: pure stores of prefetched pm centers.
#pragma unroll
        for (int j = 0; j < 8; ++j) {
            int ch = ((j >> 1) << 4) + g * 2 + (j & 1);
            *(float2*)(out + (chbase + ch) * HW_ + y * W_ + x0) = pmc[j];
        }
    } else {
        // Cold path (not taken on this data; correctness only).
        float w0[KK], w1[KK];
#pragma unroll
        for (int k = 0; k < KK; ++k) {
            w0[k] = ls[k * 64 + x0];
            w1[k] = ls[k * 64 + x0 + 1];
        }
        int cb[3];
#pragma unroll
        for (int i = 0; i < 3; ++i)
            cb[i] = min(max(x0 - 2 + 2 * i, 0), W_ - 2);
#pragma unroll
        for (int j = 0; j < 8; ++j) {
            int ch = ((j >> 1) << 4) + g * 2 + (j & 1);
            const float* pch = pm + (chbase + ch) * HW_;
            float v0 = 0.f, v1 = 0.f;
#pragma unroll
            for (int ky = 0; ky < 5; ++ky) {
                float2 t2[3];
#pragma unroll
                for (int i = 0; i < 3; ++i)
                    t2[i] = *(const float2*)(pch + qy[ky] * W_ + cb[i]);
                float v[6] = { t2[0].x, t2[0].y, t2[1].x,
                               t2[1].y, t2[2].x, t2[2].y };
#pragma unroll
                for (int kx = 0; kx < 5; ++kx) {
                    v0 = fmaf(w0[ky * 5 + kx], v[kx],     v0);
                    v1 = fmaf(w1[ky * 5 + kx], v[kx + 1], v1);
                }
            }
            float2 o;
            o.x = (zf0 != 0.f) ? pmc[j].x : v0;
            o.y = (zf1 != 0.f) ? pmc[j].y : v1;
            *(float2*)(out + (chbase + ch) * HW_ + y * W_ + x0) = o;
        }
    }
}

extern "C" void kernel_launch(void* const* d_in, const int* in_sizes, int n_in,
                              void* d_out, int out_size, void* d_ws, size_t ws_size,
                              hipStream_t stream)
{
    const float* cur  = (const float*)d_in[0];
    const float* prev = (const float*)d_in[1];
    const float* pm   = (const float*)d_in[2];
    float*       out  = (float*)d_out;
    unsigned int* pc  = (unsigned int*)d_ws;        // 512 partials (cur)
    unsigned int* pq  = pc + 512;                   // 512 partials (prev)
    unsigned int* pr  = pq + 512;                   // 512 partials (pm, unused)

    count_nz_kernel<<<512, 256, 0, stream>>>(
        (const float4*)cur, (const float4*)prev, (const float4*)pm, pc, pq, pr);

    feature_align_kernel<<<512, 256, 0, stream>>>(cur, prev, pm, out, pc, pq);
}